// Round 11
// baseline (471.688 us; speedup 1.0000x reference)
//
#include <hip/hip_runtime.h>
#include <hip/hip_bf16.h>

typedef __hip_bfloat16 bf16t;
typedef short bf16x8 __attribute__((ext_vector_type(8)));
typedef float f32x4 __attribute__((ext_vector_type(4)));

__device__ __forceinline__ unsigned short f2b(float f) {
    unsigned u;
    __builtin_memcpy(&u, &f, 4);
    unsigned r = (u + 0x7fffu + ((u >> 16) & 1u)) >> 16;  // RNE
    return (unsigned short)r;
}

__device__ __forceinline__ void gload_lds16(const void* g, void* l) {
    __builtin_amdgcn_global_load_lds(
        (const __attribute__((address_space(1))) void*)g,
        (__attribute__((address_space(3))) void*)l,
        16, 0, 0);
}

// ===========================================================================
// Merged QKV projection (R9/R10-proven): 256x256-tile NT GEMM, BK=32,
// 512 thr, 4 LDS K-tile buffers, stage-ahead-3, vmcnt(8). N=12288:
// cols<8192 -> linear Q/K (adjacent buffers), cols>=8192 -> Vt transposed.
// ===========================================================================
__global__ __launch_bounds__(512, 2)
void gemm_qkv(const bf16t* __restrict__ Ag, const bf16t* __restrict__ Bg,
              bf16t* __restrict__ Cg, const float* __restrict__ bias,
              bf16t* __restrict__ VtB, long cOffB)
{
    __shared__ __align__(16) char lds8[131072];

    unsigned gx = gridDim.x, gy = gridDim.y;
    unsigned nwg = gx * gy;
    unsigned wg = blockIdx.y * gx + blockIdx.x;
    if ((nwg & 7u) == 0u) wg = (wg & 7u) * (nwg >> 3) + (wg >> 3);
    const unsigned py = wg / gx;
    const unsigned px = wg - py * gx;
    const int brow = py * 256;
    const int bcol = px * 256;

    const size_t ldab = 1024;
    const size_t ldbb = 1024;
    const char* Agb = (const char*)Ag + (size_t)brow * ldab;
    const char* Bgb = (const char*)Bg + (size_t)bcol * ldbb;

    const int t    = threadIdx.x;
    const int lane = t & 63;
    const int wid  = t >> 6;
    const int wm   = wid >> 2;
    const int wn   = wid & 3;
    const int lr   = lane & 15;
    const int lk   = lane >> 4;

    const int srow = t >> 2;
    const int scg  = (t & 3) ^ ((srow >> 1) & 3);
    const size_t aSrc = (size_t)srow * ldab + (size_t)scg * 16;
    const size_t bSrc = (size_t)srow * ldbb + (size_t)scg * 16;
    const int dst0 = t * 16;
    char* ldsA = lds8;
    char* ldsB = lds8 + 65536;

    const int rchunk = lk ^ ((lr >> 1) & 3);
    const int aByte = (wm * 128 + lr) * 64 + rchunk * 16;
    const int bByte = (wn * 64 + lr) * 64 + rchunk * 16;

    f32x4 acc[8][4];
#pragma unroll
    for (int i = 0; i < 8; ++i)
#pragma unroll
        for (int j = 0; j < 4; ++j)
            acc[i][j] = (f32x4){0.f, 0.f, 0.f, 0.f};

    const int nk = 16;

#define STAGE_A(kt, bufi) do {                                              \
        const char* s_ = Agb + (size_t)(kt) * 64 + aSrc;                    \
        char* d_ = ldsA + (bufi) * 16384 + dst0;                            \
        gload_lds16(s_, d_);                                                \
        gload_lds16(s_ + 128 * ldab, d_ + 8192);                            \
    } while (0)
#define STAGE_B(kt, bufi) do {                                              \
        const char* s_ = Bgb + (size_t)(kt) * 64 + bSrc;                    \
        char* d_ = ldsB + (bufi) * 16384 + dst0;                            \
        gload_lds16(s_, d_);                                                \
        gload_lds16(s_ + 128 * ldbb, d_ + 8192);                            \
    } while (0)

    for (int p = 0; p < 3; ++p) { STAGE_A(p, p & 3); STAGE_B(p, p & 3); }
    asm volatile("s_waitcnt vmcnt(8)" ::: "memory");
    __builtin_amdgcn_s_barrier();

    for (int kt = 0; kt < nk; ++kt) {
        const int buf  = kt & 3;
        const int bufS = (kt + 3) & 3;
        const bool st  = (kt + 3) < nk;
        const char* lA = ldsA + buf * 16384;
        const char* lB = ldsB + buf * 16384;

        bf16x8 af[4], bfv[4];
#pragma unroll
        for (int i = 0; i < 4; ++i) af[i]  = *(const bf16x8*)(lA + aByte + i * 1024);
#pragma unroll
        for (int j = 0; j < 4; ++j) bfv[j] = *(const bf16x8*)(lB + bByte + j * 1024);
        if (st) STAGE_A(kt + 3, bufS);
        __builtin_amdgcn_s_barrier();
        asm volatile("s_waitcnt lgkmcnt(0)" ::: "memory");
        __builtin_amdgcn_s_setprio(1);
#pragma unroll
        for (int i = 0; i < 4; ++i)
#pragma unroll
            for (int j = 0; j < 4; ++j)
                acc[i][j] = __builtin_amdgcn_mfma_f32_16x16x32_bf16(af[i], bfv[j], acc[i][j], 0, 0, 0);
        __builtin_amdgcn_s_setprio(0);
        asm volatile("" ::: "memory");
        __builtin_amdgcn_s_barrier();

        bf16x8 af2[4];
#pragma unroll
        for (int i = 0; i < 4; ++i) af2[i] = *(const bf16x8*)(lA + aByte + (i + 4) * 1024);
        if (st) STAGE_B(kt + 3, bufS);
        if (st)                  asm volatile("s_waitcnt vmcnt(8)" ::: "memory");
        else if (kt + 2 < nk)    asm volatile("s_waitcnt vmcnt(4)" ::: "memory");
        else if (kt + 1 < nk)    asm volatile("s_waitcnt vmcnt(0)" ::: "memory");
        __builtin_amdgcn_s_barrier();
        asm volatile("s_waitcnt lgkmcnt(0)" ::: "memory");
        __builtin_amdgcn_s_setprio(1);
#pragma unroll
        for (int i = 0; i < 4; ++i)
#pragma unroll
            for (int j = 0; j < 4; ++j)
                acc[i + 4][j] = __builtin_amdgcn_mfma_f32_16x16x32_bf16(af2[i], bfv[j], acc[i + 4][j], 0, 0, 0);
        __builtin_amdgcn_s_setprio(0);
        asm volatile("" ::: "memory");
        __builtin_amdgcn_s_barrier();
    }
#undef STAGE_A
#undef STAGE_B

    const int sel = bcol >> 12;
    const int colw0 = bcol & 4095;
    if (sel < 2) {
        __syncthreads();
        unsigned short* lC = (unsigned short*)lds8;
#pragma unroll
        for (int i = 0; i < 8; ++i)
#pragma unroll
            for (int j = 0; j < 4; ++j) {
                int col = wn * 64 + j * 16 + lr;
                float badd = bias[bcol + col];
#pragma unroll
                for (int r = 0; r < 4; ++r) {
                    int row = wm * 128 + i * 16 + lk * 4 + r;
                    lC[row * 256 + col] = f2b(acc[i][j][r] + badd);
                }
            }
        __syncthreads();
        unsigned short* C = (unsigned short*)(Cg + (size_t)sel * cOffB);
#pragma unroll
        for (int p = 0; p < 16; ++p) {
            int c  = p * 512 + t;
            int row = c >> 5;
            int cc  = c & 31;
            bf16x8 v = *(const bf16x8*)(lC + (size_t)c * 8);
            *(bf16x8*)(C + (size_t)(brow + row) * 4096 + colw0 + cc * 8) = v;
        }
    } else {
        unsigned short* C = (unsigned short*)VtB;
#pragma unroll
        for (int i = 0; i < 8; ++i)
#pragma unroll
            for (int j = 0; j < 4; ++j) {
                int col = colw0 + wn * 64 + j * 16 + lr;
                int hh = col >> 9, dd = col & 511;
                float badd = bias[8192 + col];
                int row0 = brow + wm * 128 + i * 16 + lk * 4;
                int bb = row0 >> 11, ss0 = row0 & 2047;
                ushort4 pack;
                pack.x = f2b(acc[i][j][0] + badd);
                pack.y = f2b(acc[i][j][1] + badd);
                pack.z = f2b(acc[i][j][2] + badd);
                pack.w = f2b(acc[i][j][3] + badd);
                size_t addr = ((((size_t)(bb * 8 + hh)) * 512 + dd) << 11) + (size_t)ss0;
                *(ushort4*)(C + addr) = pack;
            }
    }
}

// ===========================================================================
// Flash-fused attention: per block (z, qt) -> 128 q-rows. Per n-tile (256 kv):
//   Phase A: accA = Q_tile K_nt^T (16 k-steps, 4-buf ahead-3 vmcnt(6),
//            R10 cadence); epilogue exp + register-rowsum + E -> LDS
//            (row-stride 512B, chunk ^= row&7 swizzle -- mandatory: all row
//            bits vanish from bank index at 512B stride).
//   Phase B: accC += E_lds @ Vt_nt^T (8 k-steps, 3-buf ahead-2 vmcnt(4)).
// E NEVER touches global. LDS: [0,96K) staging (time-shared A/B phases),
// [96K,160K) E tile. 160 KiB total, 1 block/CU.
// Grid: 256 blocks = 16 z x 16 qt.
// ===========================================================================
__global__ __launch_bounds__(512, 1)
void attn_flash(const bf16t* __restrict__ Qg, const bf16t* __restrict__ Kg,
                const bf16t* __restrict__ Vtg, bf16t* __restrict__ Cg,
                float scale)
{
    __shared__ __align__(16) char lds[163840];

    unsigned bid = blockIdx.x;
    unsigned swz = (bid & 7u) * 32u + (bid >> 3);   // XCD swizzle (256%8==0)
    const int z  = swz >> 4, qt = swz & 15;
    const int zb = z >> 3, zh = z & 7;

    const int t    = threadIdx.x;
    const int lane = t & 63;
    const int wid  = t >> 6;
    const int wm   = wid >> 2;        // 0..1
    const int wn   = wid & 3;         // 0..3
    const int lr   = lane & 15;
    const int lk   = lane >> 4;

    const size_t ldq = 8192;  // Q/K row stride bytes (4096 elems)
    const char* Agb = (const char*)Qg + ((size_t)(zb * 2048 + qt * 128) * 4096 + (size_t)zh * 512) * 2;
    const char* Kgb = (const char*)Kg + ((size_t)(zb * 2048) * 4096 + (size_t)zh * 512) * 2;
    const char* Vgb = (const char*)Vtg + (size_t)z * 512 * 2048 * 2;

    const int srow = t >> 2;
    const int scg  = (t & 3) ^ ((srow >> 1) & 3);
    const size_t qSrc = (size_t)srow * ldq + (size_t)scg * 16;
    const size_t vSrc = (size_t)srow * 4096 + (size_t)scg * 16;
    char* ldsQ = lds;                 // 4 x 8K
    char* ldsK = lds + 32768;         // 4 x 16K
    char* ldsV = lds;                 // 3 x 32K (phase B, time-shared)
    char* Elds = lds + 98304;         // 64K: E[128][256], row stride 512B

    const int rchunk = lk ^ ((lr >> 1) & 3);
    const int aByte = (wm * 64 + lr) * 64 + rchunk * 16;    // Q frag
    const int bByte = (wn * 64 + lr) * 64 + rchunk * 16;    // K frag
    const int vByte = (wn * 128 + lr) * 64 + rchunk * 16;   // Vt frag

    f32x4 accC[4][8];
#pragma unroll
    for (int i = 0; i < 4; ++i)
#pragma unroll
        for (int j = 0; j < 8; ++j)
            accC[i][j] = (f32x4){0.f, 0.f, 0.f, 0.f};
    float rs[4][4];
#pragma unroll
    for (int i = 0; i < 4; ++i)
#pragma unroll
        for (int r = 0; r < 4; ++r)
            rs[i][r] = 0.f;

#define STG_QK(nt, ks, bufi) do {                                           \
        gload_lds16(Agb + (size_t)(ks) * 64 + qSrc,                         \
                    ldsQ + (bufi) * 8192 + t * 16);                         \
        const char* sk_ = Kgb + (size_t)(nt) * 256 * ldq                    \
                          + (size_t)(ks) * 64 + qSrc;                       \
        char* dk_ = ldsK + (bufi) * 16384 + t * 16;                         \
        gload_lds16(sk_, dk_);                                              \
        gload_lds16(sk_ + 128 * ldq, dk_ + 8192);                           \
    } while (0)
#define STG_V(nt, c, bufi) do {                                             \
        const char* sv_ = Vgb + (size_t)(nt) * 512 + (size_t)(c) * 64 + vSrc;\
        char* dv_ = ldsV + (bufi) * 32768 + t * 16;                         \
        gload_lds16(sv_,              dv_);                                 \
        gload_lds16(sv_ + 128 * 4096, dv_ + 8192);                          \
        gload_lds16(sv_ + 256 * 4096, dv_ + 16384);                         \
        gload_lds16(sv_ + 384 * 4096, dv_ + 24576);                         \
    } while (0)

    for (int nt = 0; nt < 8; ++nt) {
        // ---------------- Phase A: accA = Q K_nt^T ----------------
        f32x4 accA[4][4];
#pragma unroll
        for (int i = 0; i < 4; ++i)
#pragma unroll
            for (int j = 0; j < 4; ++j)
                accA[i][j] = (f32x4){0.f, 0.f, 0.f, 0.f};

        STG_QK(nt, 0, 0); STG_QK(nt, 1, 1); STG_QK(nt, 2, 2);
        asm volatile("s_waitcnt vmcnt(6)" ::: "memory");
        __builtin_amdgcn_s_barrier();

        for (int ks = 0; ks < 16; ++ks) {
            const int buf = ks & 3;
            const char* lA = ldsQ + buf * 8192;
            const char* lB = ldsK + buf * 16384;

            bf16x8 af[4], bfv[4];
#pragma unroll
            for (int i = 0; i < 4; ++i) af[i]  = *(const bf16x8*)(lA + aByte + i * 1024);
#pragma unroll
            for (int j = 0; j < 4; ++j) bfv[j] = *(const bf16x8*)(lB + bByte + j * 1024);

            if (ks + 3 < 16) {
                STG_QK(nt, ks + 3, (ks + 3) & 3);
                asm volatile("s_waitcnt vmcnt(6)" ::: "memory");
            } else if (ks + 2 < 16) {
                asm volatile("s_waitcnt vmcnt(3)" ::: "memory");
            } else if (ks + 1 < 16) {
                asm volatile("s_waitcnt vmcnt(0)" ::: "memory");
            }
            __builtin_amdgcn_s_barrier();
            asm volatile("s_waitcnt lgkmcnt(0)" ::: "memory");
            __builtin_amdgcn_s_setprio(1);
#pragma unroll
            for (int i = 0; i < 4; ++i)
#pragma unroll
                for (int j = 0; j < 4; ++j)
                    accA[i][j] = __builtin_amdgcn_mfma_f32_16x16x32_bf16(af[i], bfv[j], accA[i][j], 0, 0, 0);
            __builtin_amdgcn_s_setprio(0);
            asm volatile("" ::: "memory");
            __builtin_amdgcn_s_barrier();
        }

        // ---- epilogue A: exp, rowsum accum, E -> LDS (swizzled) ----
        unsigned short* Ew = (unsigned short*)Elds;
#pragma unroll
        for (int i = 0; i < 4; ++i)
#pragma unroll
            for (int j = 0; j < 4; ++j) {
                int col = wn * 64 + j * 16 + lr;
#pragma unroll
                for (int r = 0; r < 4; ++r) {
                    float e = __expf(accA[i][j][r] * scale);
                    accA[i][j][r] = e;
                    int row = wm * 64 + i * 16 + lk * 4 + r;
                    int slot = (col >> 3) ^ (row & 7);
                    Ew[row * 256 + slot * 8 + (col & 7)] = f2b(e);
                }
            }
#pragma unroll
        for (int i = 0; i < 4; ++i)
#pragma unroll
            for (int r = 0; r < 4; ++r)
                rs[i][r] += accA[i][0][r] + accA[i][1][r] + accA[i][2][r] + accA[i][3][r];
        asm volatile("s_waitcnt lgkmcnt(0)" ::: "memory");
        __builtin_amdgcn_s_barrier();

        // ---------------- Phase B: accC += E @ Vt_nt^T ----------------
        STG_V(nt, 0, 0); STG_V(nt, 1, 1);
        asm volatile("s_waitcnt vmcnt(4)" ::: "memory");
        __builtin_amdgcn_s_barrier();

        for (int c = 0; c < 8; ++c) {
            const int bufv = c % 3;
            const char* lV = ldsV + bufv * 32768;

            bf16x8 afE[4], bfvV[8];
#pragma unroll
            for (int i = 0; i < 4; ++i) {
                int row = wm * 64 + i * 16 + lr;
                int slot = (c * 4 + lk) ^ (lr & 7);
                afE[i] = *(const bf16x8*)(Elds + (size_t)row * 512 + (size_t)slot * 16);
            }
#pragma unroll
            for (int j = 0; j < 8; ++j) bfvV[j] = *(const bf16x8*)(lV + vByte + j * 1024);

            if (c + 2 < 8) {
                STG_V(nt, c + 2, (c + 2) % 3);
                asm volatile("s_waitcnt vmcnt(4)" ::: "memory");
            } else if (c + 1 < 8) {
                asm volatile("s_waitcnt vmcnt(0)" ::: "memory");
            }
            __builtin_amdgcn_s_barrier();
            asm volatile("s_waitcnt lgkmcnt(0)" ::: "memory");
            __builtin_amdgcn_s_setprio(1);
#pragma unroll
            for (int i = 0; i < 4; ++i)
#pragma unroll
                for (int j = 0; j < 8; ++j)
                    accC[i][j] = __builtin_amdgcn_mfma_f32_16x16x32_bf16(afE[i], bfvV[j], accC[i][j], 0, 0, 0);
            __builtin_amdgcn_s_setprio(0);
            asm volatile("" ::: "memory");
            __builtin_amdgcn_s_barrier();
        }
    }
#undef STG_QK
#undef STG_V

    // ---- rowsum cross-wave reduce -> inv ----
#pragma unroll
    for (int i = 0; i < 4; ++i)
#pragma unroll
        for (int r = 0; r < 4; ++r) {
            float v = rs[i][r];
            v += __shfl_xor(v, 1);
            v += __shfl_xor(v, 2);
            v += __shfl_xor(v, 4);
            v += __shfl_xor(v, 8);
            rs[i][r] = v;
        }
    __syncthreads();   // phase-B LDS reads done everywhere
    float* tbl = (float*)Elds;
    if (lr == 0) {
#pragma unroll
        for (int i = 0; i < 4; ++i)
#pragma unroll
            for (int r = 0; r < 4; ++r)
                tbl[(wm * 64 + i * 16 + lk * 4 + r) * 4 + wn] = rs[i][r];
    }
    __syncthreads();
    float inv_[4][4];
#pragma unroll
    for (int i = 0; i < 4; ++i)
#pragma unroll
        for (int r = 0; r < 4; ++r) {
            int row = wm * 64 + i * 16 + lk * 4 + r;
            float4 v4 = *(const float4*)(tbl + row * 4);
            inv_[i][r] = 1.0f / (v4.x + v4.y + v4.z + v4.w);
        }

    // ---- ctx epilogue: normalize + LDS-staged coalesced write ----
    unsigned short* lC = (unsigned short*)lds;
    unsigned short* C = (unsigned short*)Cg + (size_t)zb * 2048 * 4096 + (size_t)zh * 512;
#pragma unroll
    for (int m = 0; m < 2; ++m) {
        __syncthreads();
        if (wm == m) {
#pragma unroll
            for (int i = 0; i < 4; ++i)
#pragma unroll
                for (int j = 0; j < 8; ++j) {
                    int col = wn * 128 + j * 16 + lr;
#pragma unroll
                    for (int r = 0; r < 4; ++r) {
                        int row = i * 16 + lk * 4 + r;
                        lC[row * 512 + col] = f2b(accC[i][j][r] * inv_[i][r]);
                    }
                }
        }
        __syncthreads();
#pragma unroll
        for (int p = 0; p < 8; ++p) {
            int c  = p * 512 + t;
            int row = c >> 6;
            int cc  = c & 63;
            bf16x8 v = *(const bf16x8*)(lC + (size_t)c * 8);
            *(bf16x8*)(C + (size_t)(qt * 128 + m * 64 + row) * 4096 + cc * 8) = v;
        }
    }
}

// ===========================================================================
// Output projection: 128x64-tile NT GEMM (fp32 out + bias), 256 threads,
// quad-buffered (48 KiB -> 3 blocks/CU), counted vmcnt(6).
// ===========================================================================
__global__ __launch_bounds__(256, 3)
void gemm_of32(const bf16t* __restrict__ Ag, const bf16t* __restrict__ Bg,
               float* __restrict__ Cg, const float* __restrict__ bias,
               int K, int lda, int ldb, int ldc)
{
    __shared__ __align__(16) char lds[49152];

    unsigned gx = gridDim.x, gy = gridDim.y;
    unsigned nwg = gx * gy;
    unsigned wg = blockIdx.y * gx + blockIdx.x;
    if ((nwg & 7u) == 0u) wg = (wg & 7u) * (nwg >> 3) + (wg >> 3);
    const unsigned py = wg / gx;
    const unsigned px = wg - py * gx;
    const int brow = py * 128;
    const int bcol = px * 64;

    const int t    = threadIdx.x;
    const int lane = t & 63;
    const int wid  = t >> 6;
    const int wr   = wid >> 1, wc = wid & 1;
    const int lr   = lane & 15;
    const int lk   = lane >> 4;

    const size_t ldab = (size_t)lda * 2;
    const size_t ldbb = (size_t)ldb * 2;
    const char* Agb = (const char*)Ag + (size_t)brow * ldab;
    const char* Bgb = (const char*)Bg + (size_t)bcol * ldbb;

    const int srow = t >> 2;
    const int scg  = (t & 3) ^ ((srow >> 1) & 3);
    const size_t aSrc = (size_t)srow * ldab + (size_t)scg * 16;
    const size_t bSrc = (size_t)srow * ldbb + (size_t)scg * 16;
    char* ldsA = lds;
    char* ldsB = lds + 32768;

    const int rchunk = lk ^ ((lr >> 1) & 3);
    const int aByte = (wr * 64 + lr) * 64 + rchunk * 16;
    const int bByte = (wc * 32 + lr) * 64 + rchunk * 16;

    f32x4 acc[4][2];
#pragma unroll
    for (int i = 0; i < 4; ++i)
#pragma unroll
        for (int j = 0; j < 2; ++j)
            acc[i][j] = (f32x4){0.f, 0.f, 0.f, 0.f};

    const int nk = K >> 5;

#define STAGE_O(kt, bufi) do {                                              \
        const char* sa_ = Agb + (size_t)(kt) * 64 + aSrc;                   \
        gload_lds16(sa_,             ldsA + (bufi) * 8192 + t * 16);        \
        gload_lds16(sa_ + 64 * ldab, ldsA + (bufi) * 8192 + 4096 + t * 16); \
        gload_lds16(Bgb + (size_t)(kt) * 64 + bSrc,                         \
                    ldsB + (bufi) * 4096 + t * 16);                         \
    } while (0)

    for (int p = 0; p < 3; ++p) STAGE_O(p, p);
    asm volatile("s_waitcnt vmcnt(6)" ::: "memory");
    __builtin_amdgcn_s_barrier();

    for (int kt = 0; kt < nk; ++kt) {
        const int buf  = kt & 3;
        const bool st  = (kt + 3) < nk;
        const char* lA = ldsA + buf * 8192;
        const char* lB = ldsB + buf * 4096;

        bf16x8 af[4], bfv[2];
#pragma unroll
        for (int i = 0; i < 4; ++i) af[i]  = *(const bf16x8*)(lA + aByte + i * 1024);
#pragma unroll
        for (int j = 0; j < 2; ++j) bfv[j] = *(const bf16x8*)(lB + bByte + j * 1024);
        if (st) STAGE_O(kt + 3, (kt + 3) & 3);
        if (st)                  asm volatile("s_waitcnt vmcnt(6)" ::: "memory");
        else if (kt + 2 < nk)    asm volatile("s_waitcnt vmcnt(3)" ::: "memory");
        else if (kt + 1 < nk)    asm volatile("s_waitcnt vmcnt(0)" ::: "memory");
        __builtin_amdgcn_s_barrier();
        asm volatile("s_waitcnt lgkmcnt(0)" ::: "memory");
        __builtin_amdgcn_s_setprio(1);
#pragma unroll
        for (int i = 0; i < 4; ++i)
#pragma unroll
            for (int j = 0; j < 2; ++j)
                acc[i][j] = __builtin_amdgcn_mfma_f32_16x16x32_bf16(af[i], bfv[j], acc[i][j], 0, 0, 0);
        __builtin_amdgcn_s_setprio(0);
        asm volatile("" ::: "memory");
        __builtin_amdgcn_s_barrier();
    }
#undef STAGE_O

    const int orow = brow + wr * 64;
    const int ocol = bcol + wc * 32;
#pragma unroll
    for (int i = 0; i < 4; ++i)
#pragma unroll
        for (int j = 0; j < 2; ++j) {
            int col = ocol + j * 16 + lr;
            float badd = bias[col];
#pragma unroll
            for (int r = 0; r < 4; ++r) {
                int row = orow + i * 16 + lk * 4 + r;
                Cg[(size_t)row * ldc + col] = acc[i][j][r] + badd;
            }
        }
}

// ---------------------------------------------------------------------------
// fp32 -> bf16 for the five 2M-element tensors + packed 12288-float QKV bias.
// ---------------------------------------------------------------------------
__global__ __launch_bounds__(256)
void cvt6(const float* __restrict__ s0, const float* __restrict__ s1,
          const float* __restrict__ s2, const float* __restrict__ s3,
          const float* __restrict__ s4,
          bf16t* __restrict__ d0, bf16t* __restrict__ d1,
          bf16t* __restrict__ d2, bf16t* __restrict__ d3,
          bf16t* __restrict__ d4,
          const float* __restrict__ bq, const float* __restrict__ bk,
          const float* __restrict__ bv, float* __restrict__ bqkv)
{
    int i = blockIdx.x * 256 + threadIdx.x;
    if (blockIdx.y == 5) {
        if (i < 3072) {
            int e = i * 4;
            const float* src = (e < 4096) ? (bq + e) : (e < 8192) ? (bk + e - 4096) : (bv + e - 8192);
            float4 f = *(const float4*)src;
            *(float4*)(bqkv + e) = f;
        }
        return;
    }
    const float* s;
    bf16t* d;
    switch (blockIdx.y) {
        case 0: s = s0; d = d0; break;
        case 1: s = s1; d = d1; break;
        case 2: s = s2; d = d2; break;
        case 3: s = s3; d = d3; break;
        default: s = s4; d = d4; break;
    }
    float4 f = ((const float4*)s)[i];
    ushort4 o;
    o.x = f2b(f.x); o.y = f2b(f.y); o.z = f2b(f.z); o.w = f2b(f.w);
    ((ushort4*)d)[i] = o;
}

extern "C" void kernel_launch(void* const* d_in, const int* in_sizes, int n_in,
                              void* d_out, int out_size, void* d_ws, size_t ws_size,
                              hipStream_t stream)
{
    const float* x  = (const float*)d_in[0];
    const float* Wq = (const float*)d_in[1];
    const float* bq = (const float*)d_in[2];
    const float* Wk = (const float*)d_in[3];
    const float* bk = (const float*)d_in[4];
    const float* Wv = (const float*)d_in[5];
    const float* bv = (const float*)d_in[6];
    const float* Wo = (const float*)d_in[7];
    const float* bo = (const float*)d_in[8];

    const int Dn = 512, En = 4096;
    const int Mn = 4096;
    const float scl = 0.044194173824159216f;  // 1/sqrt(512)

    bf16t* base = (bf16t*)d_ws;
    size_t off = 0;
    bf16t* Qb  = base + off; off += (size_t)Mn * En;   // Q (ctx later); K adjacent
    bf16t* Kb  = base + off; off += (size_t)Mn * En;
    bf16t* Vt  = base + off; off += (size_t)Mn * En;   // [b,h,512,2048]
    bf16t* Xb  = base + off; off += (size_t)Mn * Dn;
    bf16t* Wc  = base + off; off += (size_t)3 * En * Dn;  // packed Wq|Wk|Wv rows
    bf16t* Wob = base + off; off += (size_t)Dn * En;
    float* Pbias = (float*)(base + off); off += 12288;

    // fp32 -> bf16 conversions + bias packing
    cvt6<<<dim3(2048, 6, 1), 256, 0, stream>>>(
        x, Wq, Wk, Wv, Wo,
        Xb, Wc, Wc + (size_t)En * Dn, Wc + (size_t)2 * En * Dn, Wob,
        bq, bk, bv, Pbias);

    // merged QKV projection: M=4096, N=12288, K=512
    gemm_qkv<<<dim3(3 * En / 256, Mn / 256, 1), 512, 0, stream>>>(
        Xb, Wc, Qb, Pbias, Vt, (long)Mn * En);

    // flash-fused attention: ctx = softmax(scale*QK^T) V, E never in global
    attn_flash<<<256, 512, 0, stream>>>(Qb, Kb, Vt, Qb, scl);

    // out = ctx @ Wo^T + bo  (fp32; M=4096, N=512, K=4096)
    gemm_of32<<<dim3(Dn / 64, Mn / 128, 1), 256, 0, stream>>>(
        Qb, Wob, (float*)d_out, bo, En, En, En, Dn);
}

// Round 12
// 311.758 us; speedup vs baseline: 1.5130x; 1.5130x over previous
//
#include <hip/hip_runtime.h>
#include <hip/hip_bf16.h>

typedef __hip_bfloat16 bf16t;
typedef short bf16x8 __attribute__((ext_vector_type(8)));
typedef float f32x4 __attribute__((ext_vector_type(4)));

__device__ __forceinline__ unsigned short f2b(float f) {
    unsigned u;
    __builtin_memcpy(&u, &f, 4);
    unsigned r = (u + 0x7fffu + ((u >> 16) & 1u)) >> 16;  // RNE
    return (unsigned short)r;
}

__device__ __forceinline__ void gload_lds16(const void* g, void* l) {
    __builtin_amdgcn_global_load_lds(
        (const __attribute__((address_space(1))) void*)g,
        (__attribute__((address_space(3))) void*)l,
        16, 0, 0);
}

// ===========================================================================
// Merged QKV projection (R9/R10-proven): 256x256-tile NT GEMM, BK=32,
// 512 thr, 4 LDS K-tile buffers, stage-ahead-3, vmcnt(8). N=12288:
// cols<8192 -> linear Q/K (adjacent buffers), cols>=8192 -> Vt transposed.
// ===========================================================================
__global__ __launch_bounds__(512, 2)
void gemm_qkv(const bf16t* __restrict__ Ag, const bf16t* __restrict__ Bg,
              bf16t* __restrict__ Cg, const float* __restrict__ bias,
              bf16t* __restrict__ VtB, long cOffB)
{
    __shared__ __align__(16) char lds8[131072];

    unsigned gx = gridDim.x, gy = gridDim.y;
    unsigned nwg = gx * gy;
    unsigned wg = blockIdx.y * gx + blockIdx.x;
    if ((nwg & 7u) == 0u) wg = (wg & 7u) * (nwg >> 3) + (wg >> 3);
    const unsigned py = wg / gx;
    const unsigned px = wg - py * gx;
    const int brow = py * 256;
    const int bcol = px * 256;

    const size_t ldab = 1024;
    const size_t ldbb = 1024;
    const char* Agb = (const char*)Ag + (size_t)brow * ldab;
    const char* Bgb = (const char*)Bg + (size_t)bcol * ldbb;

    const int t    = threadIdx.x;
    const int lane = t & 63;
    const int wid  = t >> 6;
    const int wm   = wid >> 2;
    const int wn   = wid & 3;
    const int lr   = lane & 15;
    const int lk   = lane >> 4;

    const int srow = t >> 2;
    const int scg  = (t & 3) ^ ((srow >> 1) & 3);
    const size_t aSrc = (size_t)srow * ldab + (size_t)scg * 16;
    const size_t bSrc = (size_t)srow * ldbb + (size_t)scg * 16;
    const int dst0 = t * 16;
    char* ldsA = lds8;
    char* ldsB = lds8 + 65536;

    const int rchunk = lk ^ ((lr >> 1) & 3);
    const int aByte = (wm * 128 + lr) * 64 + rchunk * 16;
    const int bByte = (wn * 64 + lr) * 64 + rchunk * 16;

    f32x4 acc[8][4];
#pragma unroll
    for (int i = 0; i < 8; ++i)
#pragma unroll
        for (int j = 0; j < 4; ++j)
            acc[i][j] = (f32x4){0.f, 0.f, 0.f, 0.f};

    const int nk = 16;

#define STAGE_A(kt, bufi) do {                                              \
        const char* s_ = Agb + (size_t)(kt) * 64 + aSrc;                    \
        char* d_ = ldsA + (bufi) * 16384 + dst0;                            \
        gload_lds16(s_, d_);                                                \
        gload_lds16(s_ + 128 * ldab, d_ + 8192);                            \
    } while (0)
#define STAGE_B(kt, bufi) do {                                              \
        const char* s_ = Bgb + (size_t)(kt) * 64 + bSrc;                    \
        char* d_ = ldsB + (bufi) * 16384 + dst0;                            \
        gload_lds16(s_, d_);                                                \
        gload_lds16(s_ + 128 * ldbb, d_ + 8192);                            \
    } while (0)

    for (int p = 0; p < 3; ++p) { STAGE_A(p, p & 3); STAGE_B(p, p & 3); }
    asm volatile("s_waitcnt vmcnt(8)" ::: "memory");
    __builtin_amdgcn_s_barrier();

    for (int kt = 0; kt < nk; ++kt) {
        const int buf  = kt & 3;
        const int bufS = (kt + 3) & 3;
        const bool st  = (kt + 3) < nk;
        const char* lA = ldsA + buf * 16384;
        const char* lB = ldsB + buf * 16384;

        bf16x8 af[4], bfv[4];
#pragma unroll
        for (int i = 0; i < 4; ++i) af[i]  = *(const bf16x8*)(lA + aByte + i * 1024);
#pragma unroll
        for (int j = 0; j < 4; ++j) bfv[j] = *(const bf16x8*)(lB + bByte + j * 1024);
        if (st) STAGE_A(kt + 3, bufS);
        __builtin_amdgcn_s_barrier();
        asm volatile("s_waitcnt lgkmcnt(0)" ::: "memory");
        __builtin_amdgcn_s_setprio(1);
#pragma unroll
        for (int i = 0; i < 4; ++i)
#pragma unroll
            for (int j = 0; j < 4; ++j)
                acc[i][j] = __builtin_amdgcn_mfma_f32_16x16x32_bf16(af[i], bfv[j], acc[i][j], 0, 0, 0);
        __builtin_amdgcn_s_setprio(0);
        asm volatile("" ::: "memory");
        __builtin_amdgcn_s_barrier();

        bf16x8 af2[4];
#pragma unroll
        for (int i = 0; i < 4; ++i) af2[i] = *(const bf16x8*)(lA + aByte + (i + 4) * 1024);
        if (st) STAGE_B(kt + 3, bufS);
        if (st)                  asm volatile("s_waitcnt vmcnt(8)" ::: "memory");
        else if (kt + 2 < nk)    asm volatile("s_waitcnt vmcnt(4)" ::: "memory");
        else if (kt + 1 < nk)    asm volatile("s_waitcnt vmcnt(0)" ::: "memory");
        __builtin_amdgcn_s_barrier();
        asm volatile("s_waitcnt lgkmcnt(0)" ::: "memory");
        __builtin_amdgcn_s_setprio(1);
#pragma unroll
        for (int i = 0; i < 4; ++i)
#pragma unroll
            for (int j = 0; j < 4; ++j)
                acc[i + 4][j] = __builtin_amdgcn_mfma_f32_16x16x32_bf16(af2[i], bfv[j], acc[i + 4][j], 0, 0, 0);
        __builtin_amdgcn_s_setprio(0);
        asm volatile("" ::: "memory");
        __builtin_amdgcn_s_barrier();
    }
#undef STAGE_A
#undef STAGE_B

    const int sel = bcol >> 12;
    const int colw0 = bcol & 4095;
    if (sel < 2) {
        __syncthreads();
        unsigned short* lC = (unsigned short*)lds8;
#pragma unroll
        for (int i = 0; i < 8; ++i)
#pragma unroll
            for (int j = 0; j < 4; ++j) {
                int col = wn * 64 + j * 16 + lr;
                float badd = bias[bcol + col];
#pragma unroll
                for (int r = 0; r < 4; ++r) {
                    int row = wm * 128 + i * 16 + lk * 4 + r;
                    lC[row * 256 + col] = f2b(acc[i][j][r] + badd);
                }
            }
        __syncthreads();
        unsigned short* C = (unsigned short*)(Cg + (size_t)sel * cOffB);
#pragma unroll
        for (int p = 0; p < 16; ++p) {
            int c  = p * 512 + t;
            int row = c >> 5;
            int cc  = c & 31;
            bf16x8 v = *(const bf16x8*)(lC + (size_t)c * 8);
            *(bf16x8*)(C + (size_t)(brow + row) * 4096 + colw0 + cc * 8) = v;
        }
    } else {
        unsigned short* C = (unsigned short*)VtB;
#pragma unroll
        for (int i = 0; i < 8; ++i)
#pragma unroll
            for (int j = 0; j < 4; ++j) {
                int col = colw0 + wn * 64 + j * 16 + lr;
                int hh = col >> 9, dd = col & 511;
                float badd = bias[8192 + col];
                int row0 = brow + wm * 128 + i * 16 + lk * 4;
                int bb = row0 >> 11, ss0 = row0 & 2047;
                ushort4 pack;
                pack.x = f2b(acc[i][j][0] + badd);
                pack.y = f2b(acc[i][j][1] + badd);
                pack.z = f2b(acc[i][j][2] + badd);
                pack.w = f2b(acc[i][j][3] + badd);
                size_t addr = ((((size_t)(bb * 8 + hh)) * 512 + dd) << 11) + (size_t)ss0;
                *(ushort4*)(C + addr) = pack;
            }
    }
}

// ===========================================================================
// Fused attention (R10 structure + z-major XCD mapping + single-pass E epi):
// per block (z, qt) -> 128 q-rows.
// Phase A: E[128 x 2048] = exp(scale * Q_tile K^T), ONE continuous
//   128-iteration K-loop (4 bufs, stage-ahead-3, vmcnt(6)); per-n-tile
//   epilogue: exp + register rowsum + single-pass LDS-staged coalesced
//   E write to block-private global scratch.
// Phase B: ctx = E @ Vt^T / rowsum (3 bufs, vmcnt(5)).
// z-major mapping: XCD x (bid&7) owns z in {2x, 2x+1} -> K/Vt panels are
// XCD-L2-local, converting exposed prefetch stalls to L2 hits.
// LDS 160K: staging [0,96K) phase A / [0,120K) phase B; epi [96K,160K).
// Grid: 256 blocks, 1 block/CU.
// ===========================================================================
__global__ __launch_bounds__(512, 1)
void attn_fused(const bf16t* __restrict__ Qg, const bf16t* __restrict__ Kg,
                const bf16t* __restrict__ Vtg, bf16t* __restrict__ Esc,
                bf16t* __restrict__ Cg, float scale)
{
    __shared__ __align__(16) char lds[163840];

    unsigned bid = blockIdx.x;
    const int xcd = bid & 7;
    const int idx = bid >> 3;                 // 0..31
    const int z   = (xcd << 1) | (idx >> 4);  // 2 z per XCD
    const int qt  = idx & 15;
    const int zb = z >> 3, zh = z & 7;

    const int t    = threadIdx.x;
    const int lane = t & 63;
    const int wid  = t >> 6;
    const int wm   = wid >> 2;        // 0..1
    const int wn   = wid & 3;         // 0..3
    const int lr   = lane & 15;
    const int lk   = lane >> 4;

    const size_t ldq = 8192;  // Q/K row stride in bytes (4096 elems)
    const char* Agb = (const char*)Qg + ((size_t)(zb * 2048 + qt * 128) * 4096 + (size_t)zh * 512) * 2;
    const char* Bgb = (const char*)Kg + ((size_t)(zb * 2048) * 4096 + (size_t)zh * 512) * 2;
    unsigned short* Eb = (unsigned short*)(Esc + ((size_t)(z * 16 + qt)) * 128 * 2048);

    const int srow = t >> 2;
    const int scg  = (t & 3) ^ ((srow >> 1) & 3);
    const size_t aSrc = (size_t)srow * ldq + (size_t)scg * 16;
    char* ldsA = lds;
    char* ldsB = lds + 32768;
    const int rchunk = lk ^ ((lr >> 1) & 3);
    const int aByte = (wm * 64 + lr) * 64 + rchunk * 16;   // + i*1024 + buf*8192
    const int bByte = (wn * 64 + lr) * 64 + rchunk * 16;   // + j*1024 + buf*16384

    f32x4 acc[4][8];
#pragma unroll
    for (int i = 0; i < 4; ++i)
#pragma unroll
        for (int j = 0; j < 8; ++j)
            acc[i][j] = (f32x4){0.f, 0.f, 0.f, 0.f};
    float rs[4][4];
#pragma unroll
    for (int i = 0; i < 4; ++i)
#pragma unroll
        for (int r = 0; r < 4; ++r)
            rs[i][r] = 0.f;

    // ---------------- Phase A ----------------
#define STG_AB(g, bufi) do {                                                \
        gload_lds16(Agb + (size_t)((g) & 15) * 64 + aSrc,                   \
                    ldsA + (bufi) * 8192 + t * 16);                         \
        const char* sb_ = Bgb + (size_t)((g) >> 4) * 256 * ldq              \
                          + (size_t)((g) & 15) * 64 + aSrc;                 \
        char* db_ = ldsB + (bufi) * 16384 + t * 16;                         \
        gload_lds16(sb_, db_);                                              \
        gload_lds16(sb_ + 128 * ldq, db_ + 8192);                           \
    } while (0)

    STG_AB(0, 0); STG_AB(1, 1); STG_AB(2, 2);
    asm volatile("s_waitcnt vmcnt(6)" ::: "memory");
    __builtin_amdgcn_s_barrier();

    for (int g = 0; g < 128; ++g) {
        const int buf = g & 3;
        const char* lA = ldsA + buf * 8192;
        const char* lB = ldsB + buf * 16384;

        bf16x8 af[4], bfv[4];
#pragma unroll
        for (int i = 0; i < 4; ++i) af[i]  = *(const bf16x8*)(lA + aByte + i * 1024);
#pragma unroll
        for (int j = 0; j < 4; ++j) bfv[j] = *(const bf16x8*)(lB + bByte + j * 1024);

        if (g + 3 < 128) {
            STG_AB(g + 3, (g + 3) & 3);
            asm volatile("s_waitcnt vmcnt(6)" ::: "memory");
        } else if (g + 2 < 128) {
            asm volatile("s_waitcnt vmcnt(3)" ::: "memory");
        } else if (g + 1 < 128) {
            asm volatile("s_waitcnt vmcnt(0)" ::: "memory");
        }
        __builtin_amdgcn_s_barrier();
        asm volatile("s_waitcnt lgkmcnt(0)" ::: "memory");
        __builtin_amdgcn_s_setprio(1);
#pragma unroll
        for (int i = 0; i < 4; ++i)
#pragma unroll
            for (int j = 0; j < 4; ++j)
                acc[i][j] = __builtin_amdgcn_mfma_f32_16x16x32_bf16(af[i], bfv[j], acc[i][j], 0, 0, 0);
        __builtin_amdgcn_s_setprio(0);
        asm volatile("" ::: "memory");
        __builtin_amdgcn_s_barrier();

        if ((g & 15) == 15) {
            const int nt = g >> 4;
            // exp + rowsum accumulate
#pragma unroll
            for (int i = 0; i < 4; ++i)
#pragma unroll
                for (int j = 0; j < 4; ++j)
#pragma unroll
                    for (int r = 0; r < 4; ++r)
                        acc[i][j][r] = __expf(acc[i][j][r] * scale);
#pragma unroll
            for (int i = 0; i < 4; ++i)
#pragma unroll
                for (int r = 0; r < 4; ++r)
                    rs[i][r] += acc[i][0][r] + acc[i][1][r] + acc[i][2][r] + acc[i][3][r];

            // single-pass LDS-staged coalesced write of the 128x256 E-subtile
            unsigned short* epi = (unsigned short*)(lds + 98304);
#pragma unroll
            for (int i = 0; i < 4; ++i)
#pragma unroll
                for (int j = 0; j < 4; ++j) {
                    int col = wn * 64 + j * 16 + lr;
#pragma unroll
                    for (int r = 0; r < 4; ++r) {
                        int row = wm * 64 + i * 16 + lk * 4 + r;
                        epi[row * 256 + col] = f2b(acc[i][j][r]);
                    }
                }
            asm volatile("s_waitcnt lgkmcnt(0)" ::: "memory");
            __builtin_amdgcn_s_barrier();
#pragma unroll
            for (int p = 0; p < 8; ++p) {
                int c  = p * 512 + t;       // 4096 chunks of 16B (128 rows)
                int row = c >> 5;           // 32 chunks per 256-col row
                int cc  = c & 31;
                bf16x8 v = *(const bf16x8*)(epi + (size_t)c * 8);
                *(bf16x8*)(Eb + (size_t)row * 2048 + nt * 256 + cc * 8) = v;
            }
            asm volatile("s_waitcnt lgkmcnt(0)" ::: "memory");
            __builtin_amdgcn_s_barrier();
            // reset acc for the next n-tile
#pragma unroll
            for (int i = 0; i < 4; ++i)
#pragma unroll
                for (int j = 0; j < 4; ++j)
                    acc[i][j] = (f32x4){0.f, 0.f, 0.f, 0.f};
        }
    }
#undef STG_AB

    // ---------------- transition: rowsum reduce, store visibility ----------
    asm volatile("s_waitcnt vmcnt(0) lgkmcnt(0)" ::: "memory");
    __builtin_amdgcn_s_barrier();

#pragma unroll
    for (int i = 0; i < 4; ++i)
#pragma unroll
        for (int r = 0; r < 4; ++r) {
            float v = rs[i][r];
            v += __shfl_xor(v, 1);
            v += __shfl_xor(v, 2);
            v += __shfl_xor(v, 4);
            v += __shfl_xor(v, 8);
            rs[i][r] = v;
        }
    float* tbl = (float*)(lds + 98304);
    if (lr == 0) {
#pragma unroll
        for (int i = 0; i < 4; ++i)
#pragma unroll
            for (int r = 0; r < 4; ++r)
                tbl[(wm * 64 + i * 16 + lk * 4 + r) * 4 + wn] = rs[i][r];
    }
    asm volatile("s_waitcnt lgkmcnt(0)" ::: "memory");
    __builtin_amdgcn_s_barrier();
    float inv_[4][4];
#pragma unroll
    for (int i = 0; i < 4; ++i)
#pragma unroll
        for (int r = 0; r < 4; ++r) {
            int row = wm * 64 + i * 16 + lk * 4 + r;
            float4 v4 = *(const float4*)(tbl + row * 4);
            inv_[i][r] = 1.0f / (v4.x + v4.y + v4.z + v4.w);
        }
    asm volatile("s_waitcnt lgkmcnt(0)" ::: "memory");
    __builtin_amdgcn_s_barrier();

    // ---------------- Phase B: ctx = E @ Vt^T * inv ----------------
    const char* A2 = (const char*)Eb;                              // 4096 B rows
    const char* B2 = (const char*)Vtg + (size_t)z * 512 * 2048 * 2;
    char* ldsA2 = lds;
    char* ldsB2 = lds + 24576;
    const size_t a2Src = (size_t)srow * 4096 + (size_t)scg * 16;
    const size_t b2Src = (size_t)srow * 4096 + (size_t)scg * 16;
    const int bByte2 = (wn * 128 + lr) * 64 + rchunk * 16;

#pragma unroll
    for (int i = 0; i < 4; ++i)
#pragma unroll
        for (int j = 0; j < 8; ++j)
            acc[i][j] = (f32x4){0.f, 0.f, 0.f, 0.f};

#define STG_PV(kt, bufi) do {                                               \
        gload_lds16(A2 + (size_t)(kt) * 64 + a2Src,                         \
                    ldsA2 + (bufi) * 8192 + t * 16);                        \
        const char* sb_ = B2 + (size_t)(kt) * 64 + b2Src;                   \
        char* db_ = ldsB2 + (bufi) * 32768 + t * 16;                        \
        gload_lds16(sb_,              db_);                                 \
        gload_lds16(sb_ + 128 * 4096, db_ + 8192);                          \
        gload_lds16(sb_ + 256 * 4096, db_ + 16384);                         \
        gload_lds16(sb_ + 384 * 4096, db_ + 24576);                         \
    } while (0)

    STG_PV(0, 0);
    STG_PV(1, 1);
    asm volatile("s_waitcnt vmcnt(5)" ::: "memory");
    __builtin_amdgcn_s_barrier();

    int bufR = 0, bufS = 2;
    for (int kt = 0; kt < 64; ++kt) {
        const char* lA = ldsA2 + bufR * 8192;
        const char* lB = ldsB2 + bufR * 32768;

        bf16x8 af[4], bfv[8];
#pragma unroll
        for (int i = 0; i < 4; ++i) af[i]  = *(const bf16x8*)(lA + aByte + i * 1024);
#pragma unroll
        for (int j = 0; j < 8; ++j) bfv[j] = *(const bf16x8*)(lB + bByte2 + j * 1024);

        if (kt + 2 < 64) {
            STG_PV(kt + 2, bufS);
            asm volatile("s_waitcnt vmcnt(5)" ::: "memory");
        } else if (kt + 1 < 64) {
            asm volatile("s_waitcnt vmcnt(0)" ::: "memory");
        }
        __builtin_amdgcn_s_barrier();
        asm volatile("s_waitcnt lgkmcnt(0)" ::: "memory");
        __builtin_amdgcn_s_setprio(1);
#pragma unroll
        for (int i = 0; i < 4; ++i)
#pragma unroll
            for (int j = 0; j < 8; ++j)
                acc[i][j] = __builtin_amdgcn_mfma_f32_16x16x32_bf16(af[i], bfv[j], acc[i][j], 0, 0, 0);
        __builtin_amdgcn_s_setprio(0);
        asm volatile("" ::: "memory");
        __builtin_amdgcn_s_barrier();

        bufR = (bufR == 2) ? 0 : bufR + 1;
        bufS = (bufS == 2) ? 0 : bufS + 1;
    }
#undef STG_PV

    // ---- ctx epilogue: normalize + LDS-staged coalesced write ----
    unsigned short* lC = (unsigned short*)lds;
    unsigned short* C = (unsigned short*)Cg + (size_t)zb * 2048 * 4096 + (size_t)zh * 512;
#pragma unroll
    for (int m = 0; m < 2; ++m) {
        __syncthreads();
        if (wm == m) {
#pragma unroll
            for (int i = 0; i < 4; ++i)
#pragma unroll
                for (int j = 0; j < 8; ++j) {
                    int col = wn * 128 + j * 16 + lr;
#pragma unroll
                    for (int r = 0; r < 4; ++r) {
                        int row = i * 16 + lk * 4 + r;
                        lC[row * 512 + col] = f2b(acc[i][j][r] * inv_[i][r]);
                    }
                }
        }
        __syncthreads();
#pragma unroll
        for (int p = 0; p < 8; ++p) {
            int c  = p * 512 + t;        // 4096 chunks (64 rows x 512 cols)
            int row = c >> 6;
            int cc  = c & 63;
            bf16x8 v = *(const bf16x8*)(lC + (size_t)c * 8);
            *(bf16x8*)(C + (size_t)(qt * 128 + m * 64 + row) * 4096 + cc * 8) = v;
        }
    }
}

// ===========================================================================
// Output projection: 128x64-tile NT GEMM (fp32 out + bias), 256 threads,
// quad-buffered (48 KiB -> 3 blocks/CU), counted vmcnt(6).
// ===========================================================================
__global__ __launch_bounds__(256, 3)
void gemm_of32(const bf16t* __restrict__ Ag, const bf16t* __restrict__ Bg,
               float* __restrict__ Cg, const float* __restrict__ bias,
               int K, int lda, int ldb, int ldc)
{
    __shared__ __align__(16) char lds[49152];

    unsigned gx = gridDim.x, gy = gridDim.y;
    unsigned nwg = gx * gy;
    unsigned wg = blockIdx.y * gx + blockIdx.x;
    if ((nwg & 7u) == 0u) wg = (wg & 7u) * (nwg >> 3) + (wg >> 3);
    const unsigned py = wg / gx;
    const unsigned px = wg - py * gx;
    const int brow = py * 128;
    const int bcol = px * 64;

    const int t    = threadIdx.x;
    const int lane = t & 63;
    const int wid  = t >> 6;
    const int wr   = wid >> 1, wc = wid & 1;
    const int lr   = lane & 15;
    const int lk   = lane >> 4;

    const size_t ldab = (size_t)lda * 2;
    const size_t ldbb = (size_t)ldb * 2;
    const char* Agb = (const char*)Ag + (size_t)brow * ldab;
    const char* Bgb = (const char*)Bg + (size_t)bcol * ldbb;

    const int srow = t >> 2;
    const int scg  = (t & 3) ^ ((srow >> 1) & 3);
    const size_t aSrc = (size_t)srow * ldab + (size_t)scg * 16;
    const size_t bSrc = (size_t)srow * ldbb + (size_t)scg * 16;
    char* ldsA = lds;
    char* ldsB = lds + 32768;

    const int rchunk = lk ^ ((lr >> 1) & 3);
    const int aByte = (wr * 64 + lr) * 64 + rchunk * 16;
    const int bByte = (wc * 32 + lr) * 64 + rchunk * 16;

    f32x4 acc[4][2];
#pragma unroll
    for (int i = 0; i < 4; ++i)
#pragma unroll
        for (int j = 0; j < 2; ++j)
            acc[i][j] = (f32x4){0.f, 0.f, 0.f, 0.f};

    const int nk = K >> 5;

#define STAGE_O(kt, bufi) do {                                              \
        const char* sa_ = Agb + (size_t)(kt) * 64 + aSrc;                   \
        gload_lds16(sa_,             ldsA + (bufi) * 8192 + t * 16);        \
        gload_lds16(sa_ + 64 * ldab, ldsA + (bufi) * 8192 + 4096 + t * 16); \
        gload_lds16(Bgb + (size_t)(kt) * 64 + bSrc,                         \
                    ldsB + (bufi) * 4096 + t * 16);                         \
    } while (0)

    for (int p = 0; p < 3; ++p) STAGE_O(p, p);
    asm volatile("s_waitcnt vmcnt(6)" ::: "memory");
    __builtin_amdgcn_s_barrier();

    for (int kt = 0; kt < nk; ++kt) {
        const int buf  = kt & 3;
        const bool st  = (kt + 3) < nk;
        const char* lA = ldsA + buf * 8192;
        const char* lB = ldsB + buf * 4096;

        bf16x8 af[4], bfv[2];
#pragma unroll
        for (int i = 0; i < 4; ++i) af[i]  = *(const bf16x8*)(lA + aByte + i * 1024);
#pragma unroll
        for (int j = 0; j < 2; ++j) bfv[j] = *(const bf16x8*)(lB + bByte + j * 1024);
        if (st) STAGE_O(kt + 3, (kt + 3) & 3);
        if (st)                  asm volatile("s_waitcnt vmcnt(6)" ::: "memory");
        else if (kt + 2 < nk)    asm volatile("s_waitcnt vmcnt(3)" ::: "memory");
        else if (kt + 1 < nk)    asm volatile("s_waitcnt vmcnt(0)" ::: "memory");
        __builtin_amdgcn_s_barrier();
        asm volatile("s_waitcnt lgkmcnt(0)" ::: "memory");
        __builtin_amdgcn_s_setprio(1);
#pragma unroll
        for (int i = 0; i < 4; ++i)
#pragma unroll
            for (int j = 0; j < 2; ++j)
                acc[i][j] = __builtin_amdgcn_mfma_f32_16x16x32_bf16(af[i], bfv[j], acc[i][j], 0, 0, 0);
        __builtin_amdgcn_s_setprio(0);
        asm volatile("" ::: "memory");
        __builtin_amdgcn_s_barrier();
    }
#undef STAGE_O

    const int orow = brow + wr * 64;
    const int ocol = bcol + wc * 32;
#pragma unroll
    for (int i = 0; i < 4; ++i)
#pragma unroll
        for (int j = 0; j < 2; ++j) {
            int col = ocol + j * 16 + lr;
            float badd = bias[col];
#pragma unroll
            for (int r = 0; r < 4; ++r) {
                int row = orow + i * 16 + lk * 4 + r;
                Cg[(size_t)row * ldc + col] = acc[i][j][r] + badd;
            }
        }
}

// ---------------------------------------------------------------------------
// fp32 -> bf16 for the five 2M-element tensors + packed 12288-float QKV bias.
// ---------------------------------------------------------------------------
__global__ __launch_bounds__(256)
void cvt6(const float* __restrict__ s0, const float* __restrict__ s1,
          const float* __restrict__ s2, const float* __restrict__ s3,
          const float* __restrict__ s4,
          bf16t* __restrict__ d0, bf16t* __restrict__ d1,
          bf16t* __restrict__ d2, bf16t* __restrict__ d3,
          bf16t* __restrict__ d4,
          const float* __restrict__ bq, const float* __restrict__ bk,
          const float* __restrict__ bv, float* __restrict__ bqkv)
{
    int i = blockIdx.x * 256 + threadIdx.x;
    if (blockIdx.y == 5) {
        if (i < 3072) {
            int e = i * 4;
            const float* src = (e < 4096) ? (bq + e) : (e < 8192) ? (bk + e - 4096) : (bv + e - 8192);
            float4 f = *(const float4*)src;
            *(float4*)(bqkv + e) = f;
        }
        return;
    }
    const float* s;
    bf16t* d;
    switch (blockIdx.y) {
        case 0: s = s0; d = d0; break;
        case 1: s = s1; d = d1; break;
        case 2: s = s2; d = d2; break;
        case 3: s = s3; d = d3; break;
        default: s = s4; d = d4; break;
    }
    float4 f = ((const float4*)s)[i];
    ushort4 o;
    o.x = f2b(f.x); o.y = f2b(f.y); o.z = f2b(f.z); o.w = f2b(f.w);
    ((ushort4*)d)[i] = o;
}

extern "C" void kernel_launch(void* const* d_in, const int* in_sizes, int n_in,
                              void* d_out, int out_size, void* d_ws, size_t ws_size,
                              hipStream_t stream)
{
    const float* x  = (const float*)d_in[0];
    const float* Wq = (const float*)d_in[1];
    const float* bq = (const float*)d_in[2];
    const float* Wk = (const float*)d_in[3];
    const float* bk = (const float*)d_in[4];
    const float* Wv = (const float*)d_in[5];
    const float* bv = (const float*)d_in[6];
    const float* Wo = (const float*)d_in[7];
    const float* bo = (const float*)d_in[8];

    const int Dn = 512, En = 4096;
    const int Mn = 4096;
    const float scl = 0.044194173824159216f;  // 1/sqrt(512)

    bf16t* base = (bf16t*)d_ws;
    size_t off = 0;
    bf16t* Qb  = base + off; off += (size_t)Mn * En;   // Q (ctx later); K adjacent
    bf16t* Kb  = base + off; off += (size_t)Mn * En;
    bf16t* Vt  = base + off; off += (size_t)Mn * En;   // [b,h,512,2048]
    bf16t* Xb  = base + off; off += (size_t)Mn * Dn;
    bf16t* Wc  = base + off; off += (size_t)3 * En * Dn;  // packed Wq|Wk|Wv rows
    bf16t* Wob = base + off; off += (size_t)Dn * En;
    float* Pbias = (float*)(base + off); off += 12288;
    bf16t* Sb  = base + off;                               // E scratch, 128 MB

    // fp32 -> bf16 conversions + bias packing
    cvt6<<<dim3(2048, 6, 1), 256, 0, stream>>>(
        x, Wq, Wk, Wv, Wo,
        Xb, Wc, Wc + (size_t)En * Dn, Wc + (size_t)2 * En * Dn, Wob,
        bq, bk, bv, Pbias);

    // merged QKV projection: M=4096, N=12288, K=512
    gemm_qkv<<<dim3(3 * En / 256, Mn / 256, 1), 512, 0, stream>>>(
        Xb, Wc, Qb, Pbias, Vt, (long)Mn * En);

    // fused attention: E=exp(scale*QK^T) -> private scratch -> ctx=(EV)/rowsum
    attn_fused<<<256, 512, 0, stream>>>(Qb, Kb, Vt, Sb, Qb, scl);

    // out = ctx @ Wo^T + bo  (fp32; M=4096, N=512, K=4096)
    gemm_of32<<<dim3(Dn / 64, Mn / 128, 1), 256, 0, stream>>>(
        Qb, Wob, (float*)d_out, bo, En, En, En, Dn);
}

// Round 14
// 293.414 us; speedup vs baseline: 1.6076x; 1.0625x over previous
//
#include <hip/hip_runtime.h>
#include <hip/hip_bf16.h>

typedef __hip_bfloat16 bf16t;
typedef short bf16x8 __attribute__((ext_vector_type(8)));
typedef float f32x4 __attribute__((ext_vector_type(4)));

__device__ __forceinline__ unsigned short f2b(float f) {
    unsigned u;
    __builtin_memcpy(&u, &f, 4);
    unsigned r = (u + 0x7fffu + ((u >> 16) & 1u)) >> 16;  // RNE
    return (unsigned short)r;
}

__device__ __forceinline__ void gload_lds16(const void* g, void* l) {
    __builtin_amdgcn_global_load_lds(
        (const __attribute__((address_space(1))) void*)g,
        (__attribute__((address_space(3))) void*)l,
        16, 0, 0);
}

// ===========================================================================
// Merged QKV projection (R9/R10-proven): 256x256-tile NT GEMM, BK=32,
// 512 thr, 4 LDS K-tile buffers, stage-ahead-3, vmcnt(8). N=12288:
// cols<8192 -> linear Q/K (adjacent buffers), cols>=8192 -> Vt transposed.
// ===========================================================================
__global__ __launch_bounds__(512, 2)
void gemm_qkv(const bf16t* __restrict__ Ag, const bf16t* __restrict__ Bg,
              bf16t* __restrict__ Cg, const float* __restrict__ bias,
              bf16t* __restrict__ VtB, long cOffB)
{
    __shared__ __align__(16) char lds8[131072];

    unsigned gx = gridDim.x, gy = gridDim.y;
    unsigned nwg = gx * gy;
    unsigned wg = blockIdx.y * gx + blockIdx.x;
    if ((nwg & 7u) == 0u) wg = (wg & 7u) * (nwg >> 3) + (wg >> 3);
    const unsigned py = wg / gx;
    const unsigned px = wg - py * gx;
    const int brow = py * 256;
    const int bcol = px * 256;

    const size_t ldab = 1024;
    const size_t ldbb = 1024;
    const char* Agb = (const char*)Ag + (size_t)brow * ldab;
    const char* Bgb = (const char*)Bg + (size_t)bcol * ldbb;

    const int t    = threadIdx.x;
    const int lane = t & 63;
    const int wid  = t >> 6;
    const int wm   = wid >> 2;
    const int wn   = wid & 3;
    const int lr   = lane & 15;
    const int lk   = lane >> 4;

    const int srow = t >> 2;
    const int scg  = (t & 3) ^ ((srow >> 1) & 3);
    const size_t aSrc = (size_t)srow * ldab + (size_t)scg * 16;
    const size_t bSrc = (size_t)srow * ldbb + (size_t)scg * 16;
    const int dst0 = t * 16;
    char* ldsA = lds8;
    char* ldsB = lds8 + 65536;

    const int rchunk = lk ^ ((lr >> 1) & 3);
    const int aByte = (wm * 128 + lr) * 64 + rchunk * 16;
    const int bByte = (wn * 64 + lr) * 64 + rchunk * 16;

    f32x4 acc[8][4];
#pragma unroll
    for (int i = 0; i < 8; ++i)
#pragma unroll
        for (int j = 0; j < 4; ++j)
            acc[i][j] = (f32x4){0.f, 0.f, 0.f, 0.f};

    const int nk = 16;

#define STAGE_A(kt, bufi) do {                                              \
        const char* s_ = Agb + (size_t)(kt) * 64 + aSrc;                    \
        char* d_ = ldsA + (bufi) * 16384 + dst0;                            \
        gload_lds16(s_, d_);                                                \
        gload_lds16(s_ + 128 * ldab, d_ + 8192);                            \
    } while (0)
#define STAGE_B(kt, bufi) do {                                              \
        const char* s_ = Bgb + (size_t)(kt) * 64 + bSrc;                    \
        char* d_ = ldsB + (bufi) * 16384 + dst0;                            \
        gload_lds16(s_, d_);                                                \
        gload_lds16(s_ + 128 * ldbb, d_ + 8192);                            \
    } while (0)

    for (int p = 0; p < 3; ++p) { STAGE_A(p, p & 3); STAGE_B(p, p & 3); }
    asm volatile("s_waitcnt vmcnt(8)" ::: "memory");
    __builtin_amdgcn_s_barrier();

    for (int kt = 0; kt < nk; ++kt) {
        const int buf  = kt & 3;
        const int bufS = (kt + 3) & 3;
        const bool st  = (kt + 3) < nk;
        const char* lA = ldsA + buf * 16384;
        const char* lB = ldsB + buf * 16384;

        bf16x8 af[4], bfv[4];
#pragma unroll
        for (int i = 0; i < 4; ++i) af[i]  = *(const bf16x8*)(lA + aByte + i * 1024);
#pragma unroll
        for (int j = 0; j < 4; ++j) bfv[j] = *(const bf16x8*)(lB + bByte + j * 1024);
        if (st) STAGE_A(kt + 3, bufS);
        __builtin_amdgcn_s_barrier();
        asm volatile("s_waitcnt lgkmcnt(0)" ::: "memory");
        __builtin_amdgcn_s_setprio(1);
#pragma unroll
        for (int i = 0; i < 4; ++i)
#pragma unroll
            for (int j = 0; j < 4; ++j)
                acc[i][j] = __builtin_amdgcn_mfma_f32_16x16x32_bf16(af[i], bfv[j], acc[i][j], 0, 0, 0);
        __builtin_amdgcn_s_setprio(0);
        asm volatile("" ::: "memory");
        __builtin_amdgcn_s_barrier();

        bf16x8 af2[4];
#pragma unroll
        for (int i = 0; i < 4; ++i) af2[i] = *(const bf16x8*)(lA + aByte + (i + 4) * 1024);
        if (st) STAGE_B(kt + 3, bufS);
        if (st)                  asm volatile("s_waitcnt vmcnt(8)" ::: "memory");
        else if (kt + 2 < nk)    asm volatile("s_waitcnt vmcnt(4)" ::: "memory");
        else if (kt + 1 < nk)    asm volatile("s_waitcnt vmcnt(0)" ::: "memory");
        __builtin_amdgcn_s_barrier();
        asm volatile("s_waitcnt lgkmcnt(0)" ::: "memory");
        __builtin_amdgcn_s_setprio(1);
#pragma unroll
        for (int i = 0; i < 4; ++i)
#pragma unroll
            for (int j = 0; j < 4; ++j)
                acc[i + 4][j] = __builtin_amdgcn_mfma_f32_16x16x32_bf16(af2[i], bfv[j], acc[i + 4][j], 0, 0, 0);
        __builtin_amdgcn_s_setprio(0);
        asm volatile("" ::: "memory");
        __builtin_amdgcn_s_barrier();
    }
#undef STAGE_A
#undef STAGE_B

    const int sel = bcol >> 12;           // 0=Q, 1=K, 2=V
    const int colw0 = bcol & 4095;
    if (sel < 2) {
        __syncthreads();
        unsigned short* lC = (unsigned short*)lds8;
#pragma unroll
        for (int i = 0; i < 8; ++i)
#pragma unroll
            for (int j = 0; j < 4; ++j) {
                int col = wn * 64 + j * 16 + lr;
                float badd = bias[bcol + col];
#pragma unroll
                for (int r = 0; r < 4; ++r) {
                    int row = wm * 128 + i * 16 + lk * 4 + r;
                    lC[row * 256 + col] = f2b(acc[i][j][r] + badd);
                }
            }
        __syncthreads();
        unsigned short* C = (unsigned short*)(Cg + (size_t)sel * cOffB);
#pragma unroll
        for (int p = 0; p < 16; ++p) {
            int c  = p * 512 + t;
            int row = c >> 5;
            int cc  = c & 31;
            bf16x8 v = *(const bf16x8*)(lC + (size_t)c * 8);
            *(bf16x8*)(C + (size_t)(brow + row) * 4096 + colw0 + cc * 8) = v;
        }
    } else {
        unsigned short* C = (unsigned short*)VtB;
#pragma unroll
        for (int i = 0; i < 8; ++i)
#pragma unroll
            for (int j = 0; j < 4; ++j) {
                int col = colw0 + wn * 64 + j * 16 + lr;
                int hh = col >> 9, dd = col & 511;
                float badd = bias[8192 + col];
                int row0 = brow + wm * 128 + i * 16 + lk * 4;
                int bb = row0 >> 11, ss0 = row0 & 2047;
                ushort4 pack;
                pack.x = f2b(acc[i][j][0] + badd);
                pack.y = f2b(acc[i][j][1] + badd);
                pack.z = f2b(acc[i][j][2] + badd);
                pack.w = f2b(acc[i][j][3] + badd);
                size_t addr = ((((size_t)(bb * 8 + hh)) * 512 + dd) << 11) + (size_t)ss0;
                *(ushort4*)(C + addr) = pack;
            }
    }
}

// ===========================================================================
// Fused attention (R10-proven): per block (z = b*8+h, qt) -> 128 q-rows.
// Phase A: E[128 x 2048] = exp(scale * Q_tile K^T) as ONE continuous
//   128-iteration K-loop (8 n-tiles x 16 k-steps, 4 LDS bufs, stage-ahead-3,
//   vmcnt(6)); per-n-tile epilogue: exp, in-register rowsum accumulate,
//   2-pass LDS-staged coalesced write to BLOCK-PRIVATE scratch (L3-hot).
// Phase B: ctx[128 x 512] = E @ Vt^T / rowsum (3 bufs, vmcnt(5));
//   normalization from phase-A register rowsums (cross-wave LDS reduce).
// Grid: 256 blocks = 16 z x 16 qt, 1 block/CU.
// ===========================================================================
__global__ __launch_bounds__(512, 1)
void attn_fused(const bf16t* __restrict__ Qg, const bf16t* __restrict__ Kg,
                const bf16t* __restrict__ Vtg, bf16t* __restrict__ Esc,
                bf16t* __restrict__ Cg, float scale)
{
    __shared__ __align__(16) char lds[131072];
    // Phase A: ldsA 4x8K [0,32K), ldsB 4x16K [32K,96K), epi 32K [96K,128K)
    // Phase B: ldsA2 3x8K [0,24K), ldsB2 3x32K [24K,120K)

    unsigned bid = blockIdx.x;
    unsigned swz = (bid & 7u) * 32u + (bid >> 3);   // XCD swizzle (256%8==0)
    const int z  = swz >> 4, qt = swz & 15;
    const int zb = z >> 3, zh = z & 7;

    const int t    = threadIdx.x;
    const int lane = t & 63;
    const int wid  = t >> 6;
    const int wm   = wid >> 2;        // 0..1
    const int wn   = wid & 3;         // 0..3
    const int lr   = lane & 15;
    const int lk   = lane >> 4;

    const size_t ldq = 8192;  // Q/K row stride in bytes (4096 elems)
    const char* Agb = (const char*)Qg + ((size_t)(zb * 2048 + qt * 128) * 4096 + (size_t)zh * 512) * 2;
    const char* Bgb = (const char*)Kg + ((size_t)(zb * 2048) * 4096 + (size_t)zh * 512) * 2;
    unsigned short* Eb = (unsigned short*)(Esc + (size_t)swz * 128 * 2048);

    const int srow = t >> 2;
    const int scg  = (t & 3) ^ ((srow >> 1) & 3);
    const size_t aSrc = (size_t)srow * ldq + (size_t)scg * 16;
    const size_t bSrc = (size_t)srow * ldq + (size_t)scg * 16;
    char* ldsA = lds;
    char* ldsB = lds + 32768;
    const int rchunk = lk ^ ((lr >> 1) & 3);
    const int aByte = (wm * 64 + lr) * 64 + rchunk * 16;   // + i*1024 + buf*8192
    const int bByte = (wn * 64 + lr) * 64 + rchunk * 16;   // + j*1024 + buf*16384

    f32x4 acc[4][8];
#pragma unroll
    for (int i = 0; i < 4; ++i)
#pragma unroll
        for (int j = 0; j < 8; ++j)
            acc[i][j] = (f32x4){0.f, 0.f, 0.f, 0.f};
    float rs[4][4];
#pragma unroll
    for (int i = 0; i < 4; ++i)
#pragma unroll
        for (int r = 0; r < 4; ++r)
            rs[i][r] = 0.f;

    // ---------------- Phase A ----------------
#define STG_AB(g, bufi) do {                                                \
        gload_lds16(Agb + (size_t)((g) & 15) * 64 + aSrc,                   \
                    ldsA + (bufi) * 8192 + t * 16);                         \
        const char* sb_ = Bgb + (size_t)((g) >> 4) * 256 * ldq              \
                          + (size_t)((g) & 15) * 64 + bSrc;                 \
        char* db_ = ldsB + (bufi) * 16384 + t * 16;                         \
        gload_lds16(sb_, db_);                                              \
        gload_lds16(sb_ + 128 * ldq, db_ + 8192);                           \
    } while (0)

    STG_AB(0, 0); STG_AB(1, 1); STG_AB(2, 2);
    asm volatile("s_waitcnt vmcnt(6)" ::: "memory");
    __builtin_amdgcn_s_barrier();

    for (int g = 0; g < 128; ++g) {
        const int buf = g & 3;
        const char* lA = ldsA + buf * 8192;
        const char* lB = ldsB + buf * 16384;

        bf16x8 af[4], bfv[4];
#pragma unroll
        for (int i = 0; i < 4; ++i) af[i]  = *(const bf16x8*)(lA + aByte + i * 1024);
#pragma unroll
        for (int j = 0; j < 4; ++j) bfv[j] = *(const bf16x8*)(lB + bByte + j * 1024);

        if (g + 3 < 128) {
            STG_AB(g + 3, (g + 3) & 3);
            asm volatile("s_waitcnt vmcnt(6)" ::: "memory");
        } else if (g + 2 < 128) {
            asm volatile("s_waitcnt vmcnt(3)" ::: "memory");
        } else if (g + 1 < 128) {
            asm volatile("s_waitcnt vmcnt(0)" ::: "memory");
        }
        __builtin_amdgcn_s_barrier();
        asm volatile("s_waitcnt lgkmcnt(0)" ::: "memory");
        __builtin_amdgcn_s_setprio(1);
#pragma unroll
        for (int i = 0; i < 4; ++i)
#pragma unroll
            for (int j = 0; j < 4; ++j)
                acc[i][j] = __builtin_amdgcn_mfma_f32_16x16x32_bf16(af[i], bfv[j], acc[i][j], 0, 0, 0);
        __builtin_amdgcn_s_setprio(0);
        asm volatile("" ::: "memory");
        __builtin_amdgcn_s_barrier();

        if ((g & 15) == 15) {
            const int nt = g >> 4;
            // exp + rowsum accumulate
#pragma unroll
            for (int i = 0; i < 4; ++i)
#pragma unroll
                for (int j = 0; j < 4; ++j)
#pragma unroll
                    for (int r = 0; r < 4; ++r)
                        acc[i][j][r] = __expf(acc[i][j][r] * scale);
#pragma unroll
            for (int i = 0; i < 4; ++i)
#pragma unroll
                for (int r = 0; r < 4; ++r)
                    rs[i][r] += acc[i][0][r] + acc[i][1][r] + acc[i][2][r] + acc[i][3][r];

            // 2-pass LDS-staged coalesced write of the 128x256 E-subtile
            unsigned short* epi = (unsigned short*)(lds + 98304);
#pragma unroll
            for (int m = 0; m < 2; ++m) {
                if (wm == m) {
#pragma unroll
                    for (int i = 0; i < 4; ++i)
#pragma unroll
                        for (int j = 0; j < 4; ++j) {
                            int col = wn * 64 + j * 16 + lr;
#pragma unroll
                            for (int r = 0; r < 4; ++r)
                                epi[(i * 16 + lk * 4 + r) * 256 + col] = f2b(acc[i][j][r]);
                        }
                }
                asm volatile("s_waitcnt lgkmcnt(0)" ::: "memory");
                __builtin_amdgcn_s_barrier();
#pragma unroll
                for (int p = 0; p < 4; ++p) {
                    int c  = p * 512 + t;       // 2048 chunks of 16B
                    int row = c >> 5;           // 32 chunks per 256-col row
                    int cc  = c & 31;
                    bf16x8 v = *(const bf16x8*)(epi + (size_t)c * 8);
                    *(bf16x8*)(Eb + (size_t)(m * 64 + row) * 2048 + nt * 256 + cc * 8) = v;
                }
                asm volatile("s_waitcnt lgkmcnt(0)" ::: "memory");
                __builtin_amdgcn_s_barrier();
            }
            // reset acc for the next n-tile
#pragma unroll
            for (int i = 0; i < 4; ++i)
#pragma unroll
                for (int j = 0; j < 4; ++j)
                    acc[i][j] = (f32x4){0.f, 0.f, 0.f, 0.f};
        }
    }
#undef STG_AB

    // ---------------- transition: rowsum reduce, store visibility ----------
    asm volatile("s_waitcnt vmcnt(0) lgkmcnt(0)" ::: "memory");
    __builtin_amdgcn_s_barrier();

#pragma unroll
    for (int i = 0; i < 4; ++i)
#pragma unroll
        for (int r = 0; r < 4; ++r) {
            float v = rs[i][r];
            v += __shfl_xor(v, 1);
            v += __shfl_xor(v, 2);
            v += __shfl_xor(v, 4);
            v += __shfl_xor(v, 8);
            rs[i][r] = v;
        }
    float* tbl = (float*)(lds + 98304);
    if (lr == 0) {
#pragma unroll
        for (int i = 0; i < 4; ++i)
#pragma unroll
            for (int r = 0; r < 4; ++r)
                tbl[(wm * 64 + i * 16 + lk * 4 + r) * 4 + wn] = rs[i][r];
    }
    asm volatile("s_waitcnt lgkmcnt(0)" ::: "memory");
    __builtin_amdgcn_s_barrier();
    float inv_[4][4];
#pragma unroll
    for (int i = 0; i < 4; ++i)
#pragma unroll
        for (int r = 0; r < 4; ++r) {
            int row = wm * 64 + i * 16 + lk * 4 + r;
            float4 v4 = *(const float4*)(tbl + row * 4);
            inv_[i][r] = 1.0f / (v4.x + v4.y + v4.z + v4.w);
        }
    asm volatile("s_waitcnt lgkmcnt(0)" ::: "memory");
    __builtin_amdgcn_s_barrier();

    // ---------------- Phase B: ctx = E @ Vt^T * inv ----------------
    const char* A2 = (const char*)Eb;                              // 4096 B rows
    const char* B2 = (const char*)Vtg + (size_t)z * 512 * 2048 * 2;
    char* ldsA2 = lds;
    char* ldsB2 = lds + 24576;
    const size_t a2Src = (size_t)srow * 4096 + (size_t)scg * 16;
    const size_t b2Src = (size_t)srow * 4096 + (size_t)scg * 16;
    const int bByte2 = (wn * 128 + lr) * 64 + rchunk * 16;

#pragma unroll
    for (int i = 0; i < 4; ++i)
#pragma unroll
        for (int j = 0; j < 8; ++j)
            acc[i][j] = (f32x4){0.f, 0.f, 0.f, 0.f};

#define STG_PV(kt, bufi) do {                                               \
        gload_lds16(A2 + (size_t)(kt) * 64 + a2Src,                         \
                    ldsA2 + (bufi) * 8192 + t * 16);                        \
        const char* sb_ = B2 + (size_t)(kt) * 64 + b2Src;                   \
        char* db_ = ldsB2 + (bufi) * 32768 + t * 16;                        \
        gload_lds16(sb_,              db_);                                 \
        gload_lds16(sb_ + 128 * 4096, db_ + 8192);                          \
        gload_lds16(sb_ + 256 * 4096, db_ + 16384);                         \
        gload_lds16(sb_ + 384 * 4096, db_ + 24576);                         \
    } while (0)

    STG_PV(0, 0);
    STG_PV(1, 1);
    asm volatile("s_waitcnt vmcnt(5)" ::: "memory");
    __builtin_amdgcn_s_barrier();

    int bufR = 0, bufS = 2;
    for (int kt = 0; kt < 64; ++kt) {
        const char* lA = ldsA2 + bufR * 8192;
        const char* lB = ldsB2 + bufR * 32768;

        bf16x8 af[4], bfv[8];
#pragma unroll
        for (int i = 0; i < 4; ++i) af[i]  = *(const bf16x8*)(lA + aByte + i * 1024);
#pragma unroll
        for (int j = 0; j < 8; ++j) bfv[j] = *(const bf16x8*)(lB + bByte2 + j * 1024);

        if (kt + 2 < 64) {
            STG_PV(kt + 2, bufS);
            asm volatile("s_waitcnt vmcnt(5)" ::: "memory");
        } else if (kt + 1 < 64) {
            asm volatile("s_waitcnt vmcnt(0)" ::: "memory");
        }
        __builtin_amdgcn_s_barrier();
        asm volatile("s_waitcnt lgkmcnt(0)" ::: "memory");
        __builtin_amdgcn_s_setprio(1);
#pragma unroll
        for (int i = 0; i < 4; ++i)
#pragma unroll
            for (int j = 0; j < 8; ++j)
                acc[i][j] = __builtin_amdgcn_mfma_f32_16x16x32_bf16(af[i], bfv[j], acc[i][j], 0, 0, 0);
        __builtin_amdgcn_s_setprio(0);
        asm volatile("" ::: "memory");
        __builtin_amdgcn_s_barrier();

        bufR = (bufR == 2) ? 0 : bufR + 1;
        bufS = (bufS == 2) ? 0 : bufS + 1;
    }
#undef STG_PV

    // ---- ctx epilogue: normalize + LDS-staged coalesced write ----
    unsigned short* lC = (unsigned short*)lds;
    unsigned short* C = (unsigned short*)Cg + (size_t)zb * 2048 * 4096 + (size_t)zh * 512;
#pragma unroll
    for (int m = 0; m < 2; ++m) {
        __syncthreads();
        if (wm == m) {
#pragma unroll
            for (int i = 0; i < 4; ++i)
#pragma unroll
                for (int j = 0; j < 8; ++j) {
                    int col = wn * 128 + j * 16 + lr;
#pragma unroll
                    for (int r = 0; r < 4; ++r) {
                        int row = i * 16 + lk * 4 + r;
                        lC[row * 512 + col] = f2b(acc[i][j][r] * inv_[i][r]);
                    }
                }
        }
        __syncthreads();
#pragma unroll
        for (int p = 0; p < 8; ++p) {
            int c  = p * 512 + t;        // 4096 chunks (64 rows x 512 cols)
            int row = c >> 6;
            int cc  = c & 63;
            bf16x8 v = *(const bf16x8*)(lC + (size_t)c * 8);
            *(bf16x8*)(C + (size_t)(qt * 128 + m * 64 + row) * 4096 + cc * 8) = v;
        }
    }
}

// ===========================================================================
// Output projection: 128x64-tile NT GEMM (fp32 out + bias), 256 threads,
// quad-buffered (48 KiB -> 3 blocks/CU), counted vmcnt(6).
// ===========================================================================
__global__ __launch_bounds__(256, 3)
void gemm_of32(const bf16t* __restrict__ Ag, const bf16t* __restrict__ Bg,
               float* __restrict__ Cg, const float* __restrict__ bias,
               int K, int lda, int ldb, int ldc)
{
    __shared__ __align__(16) char lds[49152];

    unsigned gx = gridDim.x, gy = gridDim.y;
    unsigned nwg = gx * gy;
    unsigned wg = blockIdx.y * gx + blockIdx.x;
    if ((nwg & 7u) == 0u) wg = (wg & 7u) * (nwg >> 3) + (wg >> 3);
    const unsigned py = wg / gx;
    const unsigned px = wg - py * gx;
    const int brow = py * 128;
    const int bcol = px * 64;

    const int t    = threadIdx.x;
    const int lane = t & 63;
    const int wid  = t >> 6;
    const int wr   = wid >> 1, wc = wid & 1;
    const int lr   = lane & 15;
    const int lk   = lane >> 4;

    const size_t ldab = (size_t)lda * 2;
    const size_t ldbb = (size_t)ldb * 2;
    const char* Agb = (const char*)Ag + (size_t)brow * ldab;
    const char* Bgb = (const char*)Bg + (size_t)bcol * ldbb;

    const int srow = t >> 2;
    const int scg  = (t & 3) ^ ((srow >> 1) & 3);
    const size_t aSrc = (size_t)srow * ldab + (size_t)scg * 16;
    const size_t bSrc = (size_t)srow * ldbb + (size_t)scg * 16;
    char* ldsA = lds;
    char* ldsB = lds + 32768;

    const int rchunk = lk ^ ((lr >> 1) & 3);
    const int aByte = (wr * 64 + lr) * 64 + rchunk * 16;
    const int bByte = (wc * 32 + lr) * 64 + rchunk * 16;

    f32x4 acc[4][2];
#pragma unroll
    for (int i = 0; i < 4; ++i)
#pragma unroll
        for (int j = 0; j < 2; ++j)
            acc[i][j] = (f32x4){0.f, 0.f, 0.f, 0.f};

    const int nk = K >> 5;

#define STAGE_O(kt, bufi) do {                                              \
        const char* sa_ = Agb + (size_t)(kt) * 64 + aSrc;                   \
        gload_lds16(sa_,             ldsA + (bufi) * 8192 + t * 16);        \
        gload_lds16(sa_ + 64 * ldab, ldsA + (bufi) * 8192 + 4096 + t * 16); \
        gload_lds16(Bgb + (size_t)(kt) * 64 + bSrc,                         \
                    ldsB + (bufi) * 4096 + t * 16);                         \
    } while (0)

    for (int p = 0; p < 3; ++p) STAGE_O(p, p);
    asm volatile("s_waitcnt vmcnt(6)" ::: "memory");
    __builtin_amdgcn_s_barrier();

    for (int kt = 0; kt < nk; ++kt) {
        const int buf  = kt & 3;
        const bool st  = (kt + 3) < nk;
        const char* lA = ldsA + buf * 8192;
        const char* lB = ldsB + buf * 4096;

        bf16x8 af[4], bfv[2];
#pragma unroll
        for (int i = 0; i < 4; ++i) af[i]  = *(const bf16x8*)(lA + aByte + i * 1024);
#pragma unroll
        for (int j = 0; j < 2; ++j) bfv[j] = *(const bf16x8*)(lB + bByte + j * 1024);
        if (st) STAGE_O(kt + 3, (kt + 3) & 3);
        if (st)                  asm volatile("s_waitcnt vmcnt(6)" ::: "memory");
        else if (kt + 2 < nk)    asm volatile("s_waitcnt vmcnt(3)" ::: "memory");
        else if (kt + 1 < nk)    asm volatile("s_waitcnt vmcnt(0)" ::: "memory");
        __builtin_amdgcn_s_barrier();
        asm volatile("s_waitcnt lgkmcnt(0)" ::: "memory");
        __builtin_amdgcn_s_setprio(1);
#pragma unroll
        for (int i = 0; i < 4; ++i)
#pragma unroll
            for (int j = 0; j < 2; ++j)
                acc[i][j] = __builtin_amdgcn_mfma_f32_16x16x32_bf16(af[i], bfv[j], acc[i][j], 0, 0, 0);
        __builtin_amdgcn_s_setprio(0);
        asm volatile("" ::: "memory");
        __builtin_amdgcn_s_barrier();
    }
#undef STAGE_O

    const int orow = brow + wr * 64;
    const int ocol = bcol + wc * 32;
#pragma unroll
    for (int i = 0; i < 4; ++i)
#pragma unroll
        for (int j = 0; j < 2; ++j) {
            int col = ocol + j * 16 + lr;
            float badd = bias[col];
#pragma unroll
            for (int r = 0; r < 4; ++r) {
                int row = orow + i * 16 + lk * 4 + r;
                Cg[(size_t)row * ldc + col] = acc[i][j][r] + badd;
            }
        }
}

// ---------------------------------------------------------------------------
// fp32 -> bf16 for the five 2M-element tensors + packed 12288-float QKV bias.
// ---------------------------------------------------------------------------
__global__ __launch_bounds__(256)
void cvt6(const float* __restrict__ s0, const float* __restrict__ s1,
          const float* __restrict__ s2, const float* __restrict__ s3,
          const float* __restrict__ s4,
          bf16t* __restrict__ d0, bf16t* __restrict__ d1,
          bf16t* __restrict__ d2, bf16t* __restrict__ d3,
          bf16t* __restrict__ d4,
          const float* __restrict__ bq, const float* __restrict__ bk,
          const float* __restrict__ bv, float* __restrict__ bqkv)
{
    int i = blockIdx.x * 256 + threadIdx.x;
    if (blockIdx.y == 5) {
        if (i < 3072) {
            int e = i * 4;
            const float* src = (e < 4096) ? (bq + e) : (e < 8192) ? (bk + e - 4096) : (bv + e - 8192);
            float4 f = *(const float4*)src;
            *(float4*)(bqkv + e) = f;
        }
        return;
    }
    const float* s;
    bf16t* d;
    switch (blockIdx.y) {
        case 0: s = s0; d = d0; break;
        case 1: s = s1; d = d1; break;
        case 2: s = s2; d = d2; break;
        case 3: s = s3; d = d3; break;
        default: s = s4; d = d4; break;
    }
    float4 f = ((const float4*)s)[i];
    ushort4 o;
    o.x = f2b(f.x); o.y = f2b(f.y); o.z = f2b(f.z); o.w = f2b(f.w);
    ((ushort4*)d)[i] = o;
}

extern "C" void kernel_launch(void* const* d_in, const int* in_sizes, int n_in,
                              void* d_out, int out_size, void* d_ws, size_t ws_size,
                              hipStream_t stream)
{
    const float* x  = (const float*)d_in[0];
    const float* Wq = (const float*)d_in[1];
    const float* bq = (const float*)d_in[2];
    const float* Wk = (const float*)d_in[3];
    const float* bk = (const float*)d_in[4];
    const float* Wv = (const float*)d_in[5];
    const float* bv = (const float*)d_in[6];
    const float* Wo = (const float*)d_in[7];
    const float* bo = (const float*)d_in[8];

    const int Dn = 512, En = 4096;
    const int Mn = 4096;
    const float scl = 0.044194173824159216f;  // 1/sqrt(512)

    bf16t* base = (bf16t*)d_ws;
    size_t off = 0;
    bf16t* Qb  = base + off; off += (size_t)Mn * En;   // Q (ctx later); K adjacent
    bf16t* Kb  = base + off; off += (size_t)Mn * En;
    bf16t* Vt  = base + off; off += (size_t)Mn * En;   // [b,h,512,2048]
    bf16t* Xb  = base + off; off += (size_t)Mn * Dn;
    bf16t* Wc  = base + off; off += (size_t)3 * En * Dn;  // packed Wq|Wk|Wv rows
    bf16t* Wob = base + off; off += (size_t)Dn * En;
    float* Pbias = (float*)(base + off); off += 12288;
    bf16t* Sb  = base + off;                               // E scratch, 128 MB

    // fp32 -> bf16 conversions + bias packing
    cvt6<<<dim3(2048, 6, 1), 256, 0, stream>>>(
        x, Wq, Wk, Wv, Wo,
        Xb, Wc, Wc + (size_t)En * Dn, Wc + (size_t)2 * En * Dn, Wob,
        bq, bk, bv, Pbias);

    // merged QKV projection: M=4096, N=12288, K=512
    gemm_qkv<<<dim3(3 * En / 256, Mn / 256, 1), 512, 0, stream>>>(
        Xb, Wc, Qb, Pbias, Vt, (long)Mn * En);

    // fused attention: E=exp(scale*QK^T) -> private scratch -> ctx=(EV)/rowsum
    attn_fused<<<256, 512, 0, stream>>>(Qb, Kb, Vt, Sb, Qb, scl);

    // out = ctx @ Wo^T + bo  (fp32; M=4096, N=512, K=4096)
    gemm_of32<<<dim3(Dn / 64, Mn / 128, 1), 256, 0, stream>>>(
        Qb, Wob, (float*)d_out, bo, En, En, En, Dn);
}